// Round 11
// baseline (199.994 us; speedup 1.0000x reference)
//
#include <hip/hip_runtime.h>
#include <hip/hip_bf16.h>
#include <math.h>

#define BATCH 8
#define NPTS 4096
#define CH 128

// exp(s/TEMP) = 2^(s * 10 * log2(e)). sqrt(10/ln2) is folded into the
// normalize scale so the GEMM accumulator is already the exp2 argument.
#define SQRT_TEMP_LOG2E 3.79828256f   // sqrt(14.4269504089)

typedef __attribute__((ext_vector_type(4))) float f32x4;
typedef __attribute__((ext_vector_type(4))) int   i32x4;
typedef __attribute__((ext_vector_type(8))) short bf16x8;

typedef __attribute__((address_space(3))) unsigned int lds_uint;
typedef __attribute__((address_space(1))) const unsigned int gbl_uint;

__device__ __forceinline__ void load_lds16(const void* g, const void* l) {
    __builtin_amdgcn_global_load_lds((gbl_uint*)g, (lds_uint*)l, 16, 0, 0);
}

// v_exp_f32 is 2^x. (__exp2f collides with a glibc math.h macro.)
__device__ __forceinline__ float fast_exp2(float x) {
    return __builtin_amdgcn_exp2f(x);
}

// ---------------------------------------------------------------------------
// Kernel 1: one-pass L2-normalize (4 threads/point, 32 ch each in registers),
// zero pos/neg. (R10's cooperative fusion failed to launch; 3-kernel
// structure restored.)
// ---------------------------------------------------------------------------
__global__ __launch_bounds__(256) void normalize_kernel(
    const float* __restrict__ f, __hip_bfloat16* __restrict__ vn,
    float* __restrict__ pos, float* __restrict__ neg)
{
    int idx = blockIdx.x * 256 + threadIdx.x;   // 0 .. 131071
    int point = idx >> 2, q = idx & 3;
    int b = point >> 12, n = point & (NPTS - 1);
    const float* base = f + (size_t)b * CH * NPTS + (size_t)(q * 32) * NPTS + n;

    float x[32];
    float ss = 0.0f;
    #pragma unroll
    for (int c = 0; c < 32; c++) {
        x[c] = base[(size_t)c * NPTS];
        ss += x[c] * x[c];
    }
    ss += __shfl_xor(ss, 1);
    ss += __shfl_xor(ss, 2);    // 4 lanes of one point share ss
    float scale = SQRT_TEMP_LOG2E / fmaxf(sqrtf(ss), 1e-12f);

    __hip_bfloat16* out = vn + (size_t)point * CH + q * 32;
    #pragma unroll
    for (int c0 = 0; c0 < 32; c0 += 8) {
        union { __hip_bfloat16 h[8]; uint4 u; } pk;
        #pragma unroll
        for (int j = 0; j < 8; j++)
            pk.h[j] = __float2bfloat16(x[c0 + j] * scale);
        *((uint4*)(out + c0)) = pk.u;
    }
    if (q == 0) pos[point] = 0.0f;
    else if (q == 1) neg[point] = 0.0f;
}

// ---------------------------------------------------------------------------
// Kernel 2: software-pipelined tile kernel.
// 1024 blocks (4/CU, all co-resident), block = fixed (rt,ct), grid-strides
// over the 8 batches. Per iteration:
//   barrier1 (vmcnt drain: prefetch issued ~1 epilogue ago -> already landed)
//   K-loop   (ds_read lB + MFMA, R9's swapped-operand dual-row structure)
//   barrier2 (all waves done reading lB)
//   issue B-staging(batch i+1) + afrag/labC/lr loads   <-- prefetch
//   epilogue (register-only exp/mask/fold + atomics)   <-- hides prefetch
// labC double-buffered; afrag regs are dead during the epilogue so the
// prefetch adds no VGPR pressure; barriers pin staging against sinking.
// Iteration i == batch i grid-wide -> 1 MB working set, L2-resident/XCD.
//
// NO fused finalize (R7/R8: per-block __threadfence serialized the grid).
// launch_bounds(256,4): 128-reg cap; WRITE_SIZE is the spill tripwire.
// ---------------------------------------------------------------------------
__global__ __launch_bounds__(256, 4) void tile_kernel(
    const __hip_bfloat16* __restrict__ vn, const int* __restrict__ labels,
    float* __restrict__ pos, float* __restrict__ neg)
{
    __shared__ short lB[128 * CH];    // 32 KB: the 128 cols of S, row-major
    __shared__ int labC[2][128];      // double-buffered col labels

    const int rt = blockIdx.x >> 5, ct = blockIdx.x & 31;
    const bool diag = (rt == ct);     // block-uniform, loop-invariant
    const int row0 = rt * 128, col0 = ct * 128;

    const int tid = threadIdx.x;
    const int w = tid >> 6, lane = tid & 63;
    const int lane15 = lane & 15, quad = lane >> 4;

    // ---- prologue: stage batch 0 ----
    {
        const __hip_bfloat16* Bb = vn + (size_t)col0 * CH;
        #pragma unroll
        for (int i = 0; i < 8; i++) {
            int ldsrow = (w * 8 + i) * 4;           // wave-uniform
            int r = ldsrow + quad;                  // row this lane feeds
            int g = lane15 ^ (r & 15);              // swizzled global chunk
            load_lds16(Bb + (size_t)r * CH + g * 8, &lB[ldsrow * CH]);
        }
    }
    if (tid < 128) labC[0][tid] = labels[col0 + tid];

    bf16x8 afrag[2][4];
    int lr[2];
    #pragma unroll
    for (int mi = 0; mi < 2; mi++) {
        const int row_l = w * 32 + mi * 16 + lane15;
        const __hip_bfloat16* Arow = vn + (size_t)(row0 + row_l) * CH;
        #pragma unroll
        for (int ks = 0; ks < 4; ks++)
            afrag[mi][ks] = *(const bf16x8*)(Arow + (ks * 4 + quad) * 8);
        lr[mi] = labels[row0 + row_l];
    }

    for (int b = 0; b < BATCH; b++) {
        __syncthreads();   // barrier1: vmcnt drain (prefetch already landed)

        // K-loop: each bfrag read feeds both row-blocks. Swapped operands
        // put S-row on lane&15 (in-lane reduction), S-col on quad*4+reg.
        f32x4 acc[2][8] = {};
        #pragma unroll
        for (int ks = 0; ks < 4; ks++) {
            const int koff = ((ks * 4 + quad) ^ lane15) << 3;   // swizzled
            #pragma unroll
            for (int ni = 0; ni < 8; ni++) {
                bf16x8 bf = *(const bf16x8*)&lB[(ni * 16 + lane15) * CH + koff];
                acc[0][ni] = __builtin_amdgcn_mfma_f32_16x16x32_bf16(
                    bf, afrag[0][ks], acc[0][ni], 0, 0, 0);
                acc[1][ni] = __builtin_amdgcn_mfma_f32_16x16x32_bf16(
                    bf, afrag[1][ks], acc[1][ni], 0, 0, 0);
            }
        }

        __syncthreads();   // barrier2: all waves done reading lB

        const int buf = b & 1;
        int lr_cur[2] = { lr[0], lr[1] };

        // ---- prefetch batch b+1 (issued BEFORE the epilogue; its ~1000
        //      register-only cycles hide the global->LDS/reg latency) ----
        if (b + 1 < BATCH) {
            const __hip_bfloat16* vb_n = vn + (size_t)(b + 1) * NPTS * CH;
            const __hip_bfloat16* Bb = vb_n + (size_t)col0 * CH;
            #pragma unroll
            for (int i = 0; i < 8; i++) {
                int ldsrow = (w * 8 + i) * 4;
                int r = ldsrow + quad;
                int g = lane15 ^ (r & 15);
                load_lds16(Bb + (size_t)r * CH + g * 8, &lB[ldsrow * CH]);
            }
            if (tid < 128) labC[buf ^ 1][tid] = labels[(b + 1) * NPTS + col0 + tid];
            #pragma unroll
            for (int mi = 0; mi < 2; mi++) {
                const int row_l = w * 32 + mi * 16 + lane15;
                const __hip_bfloat16* Arow = vb_n + (size_t)(row0 + row_l) * CH;
                #pragma unroll
                for (int ks = 0; ks < 4; ks++)
                    afrag[mi][ks] = *(const bf16x8*)(Arow + (ks * 4 + quad) * 8);
                lr[mi] = labels[(b + 1) * NPTS + row0 + row_l];
            }
        }

        // ---- epilogue for batch b: in-lane sums, fold quads, atomics ----
        #pragma unroll
        for (int mi = 0; mi < 2; mi++) {
            const int row_l = w * 32 + mi * 16 + lane15;
            float p = 0.0f, tt = 0.0f;
            if (diag) {
                #pragma unroll
                for (int ni = 0; ni < 8; ni++) {
                    const bool dblk = (ni * 16 == w * 32 + mi * 16);
                    const i32x4 lc = *(const i32x4*)&labC[buf][ni * 16 + quad * 4];
                    #pragma unroll
                    for (int r = 0; r < 4; r++) {
                        float e = fast_exp2(acc[mi][ni][r]);
                        if (dblk && lane15 == quad * 4 + r) e = 0.0f;
                        tt += e;
                        p  += (lc[r] == lr_cur[mi]) ? e : 0.0f;
                    }
                }
            } else {
                #pragma unroll
                for (int ni = 0; ni < 8; ni++) {
                    const i32x4 lc = *(const i32x4*)&labC[buf][ni * 16 + quad * 4];
                    #pragma unroll
                    for (int r = 0; r < 4; r++) {
                        float e = fast_exp2(acc[mi][ni][r]);
                        tt += e;
                        p  += (lc[r] == lr_cur[mi]) ? e : 0.0f;
                    }
                }
            }
            p  += __shfl_xor(p, 16);   p  += __shfl_xor(p, 32);
            tt += __shfl_xor(tt, 16);  tt += __shfl_xor(tt, 32);
            if (lane < 16) {
                atomicAdd(&pos[b * NPTS + row0 + row_l], p);
                atomicAdd(&neg[b * NPTS + row0 + row_l], tt - p);
            }
        }
    }
}

// ---------------------------------------------------------------------------
// Kernel 3: mean of log((p+n)/p) over 32768 rows. Single block, 1024 thr.
// ---------------------------------------------------------------------------
__global__ __launch_bounds__(1024) void finalize_kernel(
    const float* __restrict__ pos, const float* __restrict__ neg,
    float* __restrict__ out)
{
    float acc = 0.0f;
    for (int i = threadIdx.x; i < BATCH * NPTS; i += 1024) {
        float p = pos[i];
        float t = p + neg[i];
        acc += __logf(t / p);   // == -log(p / (p+n))
    }
    #pragma unroll
    for (int off = 32; off; off >>= 1) acc += __shfl_down(acc, off);
    __shared__ float red[16];
    if ((threadIdx.x & 63) == 0) red[threadIdx.x >> 6] = acc;
    __syncthreads();
    if (threadIdx.x < 16) {
        float v = red[threadIdx.x];
        #pragma unroll
        for (int off = 8; off; off >>= 1) v += __shfl_down(v, off);
        if (threadIdx.x == 0) out[0] = v * (1.0f / (BATCH * NPTS));
    }
}

extern "C" void kernel_launch(void* const* d_in, const int* in_sizes, int n_in,
                              void* d_out, int out_size, void* d_ws, size_t ws_size,
                              hipStream_t stream)
{
    const float* features = (const float*)d_in[0];
    const int*   labels   = (const int*)d_in[1];
    float*       out      = (float*)d_out;

    // Workspace: vn bf16 [8][4096][128] = 8 MB, then pos/neg fp32.
    __hip_bfloat16* vn = (__hip_bfloat16*)d_ws;
    float* pos = (float*)((char*)d_ws + (size_t)BATCH * NPTS * CH * sizeof(__hip_bfloat16));
    float* neg = pos + BATCH * NPTS;

    hipLaunchKernelGGL(normalize_kernel, dim3(BATCH * NPTS * 4 / 256), dim3(256), 0, stream,
                       features, vn, pos, neg);
    // 1024 blocks = 32x32 tiles; each block grid-strides over the 8 batches.
    hipLaunchKernelGGL(tile_kernel, dim3(1024), dim3(256), 0, stream,
                       vn, labels, pos, neg);
    hipLaunchKernelGGL(finalize_kernel, dim3(1), dim3(1024), 0, stream, pos, neg, out);
}

// Round 12
// 197.460 us; speedup vs baseline: 1.0128x; 1.0128x over previous
//
#include <hip/hip_runtime.h>
#include <hip/hip_bf16.h>
#include <math.h>

#define BATCH 8
#define NPTS 4096
#define CH 128

// exp(s/TEMP) = 2^(s * 10 * log2(e)). sqrt(10/ln2) is folded into the
// normalize scale so the GEMM accumulator is already the exp2 argument.
#define SQRT_TEMP_LOG2E 3.79828256f   // sqrt(14.4269504089)

typedef __attribute__((ext_vector_type(4))) float f32x4;
typedef __attribute__((ext_vector_type(4))) int   i32x4;
typedef __attribute__((ext_vector_type(8))) short bf16x8;

typedef __attribute__((address_space(3))) unsigned int lds_uint;
typedef __attribute__((address_space(1))) const unsigned int gbl_uint;

__device__ __forceinline__ void load_lds16(const void* g, const void* l) {
    __builtin_amdgcn_global_load_lds((gbl_uint*)g, (lds_uint*)l, 16, 0, 0);
}

// v_exp_f32 is 2^x. (__exp2f collides with a glibc math.h macro.)
__device__ __forceinline__ float fast_exp2(float x) {
    return __builtin_amdgcn_exp2f(x);
}

// ---------------------------------------------------------------------------
// Kernel 1: one-pass L2-normalize (4 threads/point, 32 ch each in registers),
// zero pos/neg.
// ---------------------------------------------------------------------------
__global__ __launch_bounds__(256) void normalize_kernel(
    const float* __restrict__ f, __hip_bfloat16* __restrict__ vn,
    float* __restrict__ pos, float* __restrict__ neg)
{
    int idx = blockIdx.x * 256 + threadIdx.x;   // 0 .. 131071
    int point = idx >> 2, q = idx & 3;
    int b = point >> 12, n = point & (NPTS - 1);
    const float* base = f + (size_t)b * CH * NPTS + (size_t)(q * 32) * NPTS + n;

    float x[32];
    float ss = 0.0f;
    #pragma unroll
    for (int c = 0; c < 32; c++) {
        x[c] = base[(size_t)c * NPTS];
        ss += x[c] * x[c];
    }
    ss += __shfl_xor(ss, 1);
    ss += __shfl_xor(ss, 2);    // 4 lanes of one point share ss
    float scale = SQRT_TEMP_LOG2E / fmaxf(sqrtf(ss), 1e-12f);

    __hip_bfloat16* out = vn + (size_t)point * CH + q * 32;
    #pragma unroll
    for (int c0 = 0; c0 < 32; c0 += 8) {
        union { __hip_bfloat16 h[8]; uint4 u; } pk;
        #pragma unroll
        for (int j = 0; j < 8; j++)
            pk.h[j] = __float2bfloat16(x[c0 + j] * scale);
        *((uint4*)(out + c0)) = pk.u;
    }
    if (q == 0) pos[point] = 0.0f;
    else if (q == 1) neg[point] = 0.0f;
}

// ---------------------------------------------------------------------------
// Kernel 2: software-pipelined tile kernel, spill-safe prefetch split.
// 1024 blocks (4/CU, co-resident), block = fixed (rt,ct), loops over the
// 8 batches. Per iteration:
//   barrier1  (vmcnt drain: B/labC prefetch issued ~1 epilogue ago)
//   K-loop    (ds_read lB + MFMA, swapped-operand dual-row structure)
//   barrier2  (all waves done reading lB)
//   prefetch B(b+1) -> lB + labC      <-- ZERO VGPR cost (direct to LDS)
//   epilogue  (register-only exp/mask/fold + atomics, hides the prefetch)
//   load afrag(b+1) + lr(b+1)         <-- after epilogue: live range
//                                         (issue -> barrier -> K-loop) is
//                                         exactly R9's, so peak regs = R9.
// R11 put the afrag prefetch BEFORE the epilogue: afrag(+32) overlapped the
// live acc(64 AGPR) at the 128-reg cap -> hot-loop spill (WRITE 184 MB).
// gfx950's unified VGPR/AGPR file means acc's 64 AGPRs count against the
// (256,4) budget — do not let afrag live through the epilogue.
//
// NO fused finalize (R7/R8: per-block __threadfence serialized the grid).
// ---------------------------------------------------------------------------
__global__ __launch_bounds__(256, 4) void tile_kernel(
    const __hip_bfloat16* __restrict__ vn, const int* __restrict__ labels,
    float* __restrict__ pos, float* __restrict__ neg)
{
    __shared__ short lB[128 * CH];    // 32 KB: the 128 cols of S, row-major
    __shared__ int labC[2][128];      // double-buffered col labels

    const int rt = blockIdx.x >> 5, ct = blockIdx.x & 31;
    const bool diag = (rt == ct);     // block-uniform, loop-invariant
    const int row0 = rt * 128, col0 = ct * 128;

    const int tid = threadIdx.x;
    const int w = tid >> 6, lane = tid & 63;
    const int lane15 = lane & 15, quad = lane >> 4;

    // ---- prologue: stage batch 0 ----
    {
        const __hip_bfloat16* Bb = vn + (size_t)col0 * CH;
        #pragma unroll
        for (int i = 0; i < 8; i++) {
            int ldsrow = (w * 8 + i) * 4;           // wave-uniform
            int r = ldsrow + quad;                  // row this lane feeds
            int g = lane15 ^ (r & 15);              // swizzled global chunk
            load_lds16(Bb + (size_t)r * CH + g * 8, &lB[ldsrow * CH]);
        }
    }
    if (tid < 128) labC[0][tid] = labels[col0 + tid];

    bf16x8 afrag[2][4];
    int lr[2];
    #pragma unroll
    for (int mi = 0; mi < 2; mi++) {
        const int row_l = w * 32 + mi * 16 + lane15;
        const __hip_bfloat16* Arow = vn + (size_t)(row0 + row_l) * CH;
        #pragma unroll
        for (int ks = 0; ks < 4; ks++)
            afrag[mi][ks] = *(const bf16x8*)(Arow + (ks * 4 + quad) * 8);
        lr[mi] = labels[row0 + row_l];
    }

    for (int b = 0; b < BATCH; b++) {
        __syncthreads();   // barrier1: vmcnt drain (prefetch already landed)

        // K-loop: each bfrag read feeds both row-blocks. Swapped operands
        // put S-row on lane&15 (in-lane reduction), S-col on quad*4+reg.
        f32x4 acc[2][8] = {};
        #pragma unroll
        for (int ks = 0; ks < 4; ks++) {
            const int koff = ((ks * 4 + quad) ^ lane15) << 3;   // swizzled
            #pragma unroll
            for (int ni = 0; ni < 8; ni++) {
                bf16x8 bf = *(const bf16x8*)&lB[(ni * 16 + lane15) * CH + koff];
                acc[0][ni] = __builtin_amdgcn_mfma_f32_16x16x32_bf16(
                    bf, afrag[0][ks], acc[0][ni], 0, 0, 0);
                acc[1][ni] = __builtin_amdgcn_mfma_f32_16x16x32_bf16(
                    bf, afrag[1][ks], acc[1][ni], 0, 0, 0);
            }
        }

        __syncthreads();   // barrier2: all waves done reading lB

        const int buf = b & 1;

        // ---- prefetch B(b+1)+labC ONLY (no registers consumed): the
        //      epilogue's ~1000 register-only cycles hide this latency ----
        if (b + 1 < BATCH) {
            const __hip_bfloat16* Bb =
                vn + (size_t)(b + 1) * NPTS * CH + (size_t)col0 * CH;
            #pragma unroll
            for (int i = 0; i < 8; i++) {
                int ldsrow = (w * 8 + i) * 4;
                int r = ldsrow + quad;
                int g = lane15 ^ (r & 15);
                load_lds16(Bb + (size_t)r * CH + g * 8, &lB[ldsrow * CH]);
            }
            if (tid < 128) labC[buf ^ 1][tid] = labels[(b + 1) * NPTS + col0 + tid];
        }

        // ---- epilogue for batch b: in-lane sums, fold quads, atomics ----
        #pragma unroll
        for (int mi = 0; mi < 2; mi++) {
            const int row_l = w * 32 + mi * 16 + lane15;
            float p = 0.0f, tt = 0.0f;
            if (diag) {
                #pragma unroll
                for (int ni = 0; ni < 8; ni++) {
                    const bool dblk = (ni * 16 == w * 32 + mi * 16);
                    const i32x4 lc = *(const i32x4*)&labC[buf][ni * 16 + quad * 4];
                    #pragma unroll
                    for (int r = 0; r < 4; r++) {
                        float e = fast_exp2(acc[mi][ni][r]);
                        if (dblk && lane15 == quad * 4 + r) e = 0.0f;
                        tt += e;
                        p  += (lc[r] == lr[mi]) ? e : 0.0f;
                    }
                }
            } else {
                #pragma unroll
                for (int ni = 0; ni < 8; ni++) {
                    const i32x4 lc = *(const i32x4*)&labC[buf][ni * 16 + quad * 4];
                    #pragma unroll
                    for (int r = 0; r < 4; r++) {
                        float e = fast_exp2(acc[mi][ni][r]);
                        tt += e;
                        p  += (lc[r] == lr[mi]) ? e : 0.0f;
                    }
                }
            }
            p  += __shfl_xor(p, 16);   p  += __shfl_xor(p, 32);
            tt += __shfl_xor(tt, 16);  tt += __shfl_xor(tt, 32);
            if (lane < 16) {
                atomicAdd(&pos[b * NPTS + row0 + row_l], p);
                atomicAdd(&neg[b * NPTS + row0 + row_l], tt - p);
            }
        }

        // ---- afrag/lr for batch b+1, AFTER the epilogue (acc now dead;
        //      live range = issue -> barrier1 -> K-loop, same as R9) ----
        if (b + 1 < BATCH) {
            const __hip_bfloat16* vb_n = vn + (size_t)(b + 1) * NPTS * CH;
            #pragma unroll
            for (int mi = 0; mi < 2; mi++) {
                const int row_l = w * 32 + mi * 16 + lane15;
                const __hip_bfloat16* Arow = vb_n + (size_t)(row0 + row_l) * CH;
                #pragma unroll
                for (int ks = 0; ks < 4; ks++)
                    afrag[mi][ks] = *(const bf16x8*)(Arow + (ks * 4 + quad) * 8);
                lr[mi] = labels[(b + 1) * NPTS + row0 + row_l];
            }
        }
    }
}

// ---------------------------------------------------------------------------
// Kernel 3: mean of log((p+n)/p) over 32768 rows. Single block, 1024 thr.
// ---------------------------------------------------------------------------
__global__ __launch_bounds__(1024) void finalize_kernel(
    const float* __restrict__ pos, const float* __restrict__ neg,
    float* __restrict__ out)
{
    float acc = 0.0f;
    for (int i = threadIdx.x; i < BATCH * NPTS; i += 1024) {
        float p = pos[i];
        float t = p + neg[i];
        acc += __logf(t / p);   // == -log(p / (p+n))
    }
    #pragma unroll
    for (int off = 32; off; off >>= 1) acc += __shfl_down(acc, off);
    __shared__ float red[16];
    if ((threadIdx.x & 63) == 0) red[threadIdx.x >> 6] = acc;
    __syncthreads();
    if (threadIdx.x < 16) {
        float v = red[threadIdx.x];
        #pragma unroll
        for (int off = 8; off; off >>= 1) v += __shfl_down(v, off);
        if (threadIdx.x == 0) out[0] = v * (1.0f / (BATCH * NPTS));
    }
}

extern "C" void kernel_launch(void* const* d_in, const int* in_sizes, int n_in,
                              void* d_out, int out_size, void* d_ws, size_t ws_size,
                              hipStream_t stream)
{
    const float* features = (const float*)d_in[0];
    const int*   labels   = (const int*)d_in[1];
    float*       out      = (float*)d_out;

    // Workspace: vn bf16 [8][4096][128] = 8 MB, then pos/neg fp32.
    __hip_bfloat16* vn = (__hip_bfloat16*)d_ws;
    float* pos = (float*)((char*)d_ws + (size_t)BATCH * NPTS * CH * sizeof(__hip_bfloat16));
    float* neg = pos + BATCH * NPTS;

    hipLaunchKernelGGL(normalize_kernel, dim3(BATCH * NPTS * 4 / 256), dim3(256), 0, stream,
                       features, vn, pos, neg);
    // 1024 blocks = 32x32 tiles; each block loops over the 8 batches.
    hipLaunchKernelGGL(tile_kernel, dim3(1024), dim3(256), 0, stream,
                       vn, labels, pos, neg);
    hipLaunchKernelGGL(finalize_kernel, dim3(1), dim3(1024), 0, stream, pos, neg, out);
}

// Round 13
// 165.357 us; speedup vs baseline: 1.2095x; 1.1941x over previous
//
#include <hip/hip_runtime.h>
#include <hip/hip_bf16.h>
#include <math.h>

#define BATCH 8
#define NPTS 4096
#define CH 128

// exp(s/TEMP) = 2^(s * 10 * log2(e)). sqrt(10/ln2) is folded into the
// normalize scale so the GEMM accumulator is already the exp2 argument.
#define SQRT_TEMP_LOG2E 3.79828256f   // sqrt(14.4269504089)

typedef __attribute__((ext_vector_type(4))) float f32x4;
typedef __attribute__((ext_vector_type(4))) int   i32x4;
typedef __attribute__((ext_vector_type(8))) short bf16x8;

typedef __attribute__((address_space(3))) unsigned int lds_uint;
typedef __attribute__((address_space(1))) const unsigned int gbl_uint;

__device__ __forceinline__ void load_lds16(const void* g, const void* l) {
    __builtin_amdgcn_global_load_lds((gbl_uint*)g, (lds_uint*)l, 16, 0, 0);
}

// v_exp_f32 is 2^x. (__exp2f collides with a glibc math.h macro.)
__device__ __forceinline__ float fast_exp2(float x) {
    return __builtin_amdgcn_exp2f(x);
}

// ---------------------------------------------------------------------------
// Kernel 1: one-pass L2-normalize (4 threads/point, 32 ch each in registers),
// zero pos/neg.
// ---------------------------------------------------------------------------
__global__ __launch_bounds__(256) void normalize_kernel(
    const float* __restrict__ f, __hip_bfloat16* __restrict__ vn,
    float* __restrict__ pos, float* __restrict__ neg)
{
    int idx = blockIdx.x * 256 + threadIdx.x;   // 0 .. 131071
    int point = idx >> 2, q = idx & 3;
    int b = point >> 12, n = point & (NPTS - 1);
    const float* base = f + (size_t)b * CH * NPTS + (size_t)(q * 32) * NPTS + n;

    float x[32];
    float ss = 0.0f;
    #pragma unroll
    for (int c = 0; c < 32; c++) {
        x[c] = base[(size_t)c * NPTS];
        ss += x[c] * x[c];
    }
    ss += __shfl_xor(ss, 1);
    ss += __shfl_xor(ss, 2);    // 4 lanes of one point share ss
    float scale = SQRT_TEMP_LOG2E / fmaxf(sqrtf(ss), 1e-12f);

    __hip_bfloat16* out = vn + (size_t)point * CH + q * 32;
    #pragma unroll
    for (int c0 = 0; c0 < 32; c0 += 8) {
        union { __hip_bfloat16 h[8]; uint4 u; } pk;
        #pragma unroll
        for (int j = 0; j < 8; j++)
            pk.h[j] = __float2bfloat16(x[c0 + j] * scale);
        *((uint4*)(out + c0)) = pk.u;
    }
    if (q == 0) pos[point] = 0.0f;
    else if (q == 1) neg[point] = 0.0f;
}

// ---------------------------------------------------------------------------
// Kernel 2: software-pipelined tile kernel with a register budget that FITS.
//
// R11/R12 lesson: at launch_bounds(256,4) the cap is 128 regs and acc(64
// AGPR, unified file) + afrag(32) cannot overlap — and the compiler hoists
// the independent afrag prefetch above the epilogue regardless of source
// order, so ANY pipelined form spills at cap 128 (WRITE_SIZE 184/213 MB).
// Fix: launch_bounds(256,3) -> ~170-reg cap. Live set ~140. 3 blocks/CU
// matches R9's MEASURED residency (~12 waves/CU) so no parallelism is lost.
//
// Per batch iteration:
//   barrier1 (vmcnt drain: prefetch issued ~1 epilogue ago -> landed)
//   K-loop   (ds_read lB + MFMA, swapped-operand dual-row structure)
//   barrier2 (all waves done reading lB)
//   prefetch B(b+1)->lB (zero-VGPR), labC, afrag(b+1), lr(b+1)
//   epilogue (register-only exp/mask/fold + atomics) hides the prefetch
//
// NO fused finalize (R7/R8: per-block __threadfence serialized the grid).
// WRITE_SIZE is the spill tripwire: must read ~8 MB.
// ---------------------------------------------------------------------------
__global__ __launch_bounds__(256, 3) void tile_kernel(
    const __hip_bfloat16* __restrict__ vn, const int* __restrict__ labels,
    float* __restrict__ pos, float* __restrict__ neg)
{
    __shared__ short lB[128 * CH];    // 32 KB: the 128 cols of S, row-major
    __shared__ int labC[2][128];      // double-buffered col labels

    const int rt = blockIdx.x >> 5, ct = blockIdx.x & 31;
    const bool diag = (rt == ct);     // block-uniform, loop-invariant
    const int row0 = rt * 128, col0 = ct * 128;

    const int tid = threadIdx.x;
    const int w = tid >> 6, lane = tid & 63;
    const int lane15 = lane & 15, quad = lane >> 4;

    // ---- prologue: stage batch 0 ----
    {
        const __hip_bfloat16* Bb = vn + (size_t)col0 * CH;
        #pragma unroll
        for (int i = 0; i < 8; i++) {
            int ldsrow = (w * 8 + i) * 4;           // wave-uniform
            int r = ldsrow + quad;                  // row this lane feeds
            int g = lane15 ^ (r & 15);              // swizzled global chunk
            load_lds16(Bb + (size_t)r * CH + g * 8, &lB[ldsrow * CH]);
        }
    }
    if (tid < 128) labC[0][tid] = labels[col0 + tid];

    bf16x8 afrag[2][4];
    int lr[2];
    #pragma unroll
    for (int mi = 0; mi < 2; mi++) {
        const int row_l = w * 32 + mi * 16 + lane15;
        const __hip_bfloat16* Arow = vn + (size_t)(row0 + row_l) * CH;
        #pragma unroll
        for (int ks = 0; ks < 4; ks++)
            afrag[mi][ks] = *(const bf16x8*)(Arow + (ks * 4 + quad) * 8);
        lr[mi] = labels[row0 + row_l];
    }

    for (int b = 0; b < BATCH; b++) {
        __syncthreads();   // barrier1: vmcnt drain (prefetch already landed)

        // K-loop: each bfrag read feeds both row-blocks. Swapped operands
        // put S-row on lane&15 (in-lane reduction), S-col on quad*4+reg.
        f32x4 acc[2][8] = {};
        #pragma unroll
        for (int ks = 0; ks < 4; ks++) {
            const int koff = ((ks * 4 + quad) ^ lane15) << 3;   // swizzled
            #pragma unroll
            for (int ni = 0; ni < 8; ni++) {
                bf16x8 bf = *(const bf16x8*)&lB[(ni * 16 + lane15) * CH + koff];
                acc[0][ni] = __builtin_amdgcn_mfma_f32_16x16x32_bf16(
                    bf, afrag[0][ks], acc[0][ni], 0, 0, 0);
                acc[1][ni] = __builtin_amdgcn_mfma_f32_16x16x32_bf16(
                    bf, afrag[1][ks], acc[1][ni], 0, 0, 0);
            }
        }

        __syncthreads();   // barrier2: all waves done reading lB

        const int buf = b & 1;
        int lr_cur[2] = { lr[0], lr[1] };

        // ---- prefetch batch b+1 (B->LDS is zero-VGPR; afrag costs 32 regs
        //      which the 170-cap absorbs; the epilogue hides the latency) ----
        if (b + 1 < BATCH) {
            const __hip_bfloat16* vb_n = vn + (size_t)(b + 1) * NPTS * CH;
            const __hip_bfloat16* Bb = vb_n + (size_t)col0 * CH;
            #pragma unroll
            for (int i = 0; i < 8; i++) {
                int ldsrow = (w * 8 + i) * 4;
                int r = ldsrow + quad;
                int g = lane15 ^ (r & 15);
                load_lds16(Bb + (size_t)r * CH + g * 8, &lB[ldsrow * CH]);
            }
            if (tid < 128) labC[buf ^ 1][tid] = labels[(b + 1) * NPTS + col0 + tid];
            #pragma unroll
            for (int mi = 0; mi < 2; mi++) {
                const int row_l = w * 32 + mi * 16 + lane15;
                const __hip_bfloat16* Arow = vb_n + (size_t)(row0 + row_l) * CH;
                #pragma unroll
                for (int ks = 0; ks < 4; ks++)
                    afrag[mi][ks] = *(const bf16x8*)(Arow + (ks * 4 + quad) * 8);
                lr[mi] = labels[(b + 1) * NPTS + row0 + row_l];
            }
        }

        // ---- epilogue for batch b: in-lane sums, fold quads, atomics ----
        #pragma unroll
        for (int mi = 0; mi < 2; mi++) {
            const int row_l = w * 32 + mi * 16 + lane15;
            float p = 0.0f, tt = 0.0f;
            if (diag) {
                #pragma unroll
                for (int ni = 0; ni < 8; ni++) {
                    const bool dblk = (ni * 16 == w * 32 + mi * 16);
                    const i32x4 lc = *(const i32x4*)&labC[buf][ni * 16 + quad * 4];
                    #pragma unroll
                    for (int r = 0; r < 4; r++) {
                        float e = fast_exp2(acc[mi][ni][r]);
                        if (dblk && lane15 == quad * 4 + r) e = 0.0f;
                        tt += e;
                        p  += (lc[r] == lr_cur[mi]) ? e : 0.0f;
                    }
                }
            } else {
                #pragma unroll
                for (int ni = 0; ni < 8; ni++) {
                    const i32x4 lc = *(const i32x4*)&labC[buf][ni * 16 + quad * 4];
                    #pragma unroll
                    for (int r = 0; r < 4; r++) {
                        float e = fast_exp2(acc[mi][ni][r]);
                        tt += e;
                        p  += (lc[r] == lr_cur[mi]) ? e : 0.0f;
                    }
                }
            }
            p  += __shfl_xor(p, 16);   p  += __shfl_xor(p, 32);
            tt += __shfl_xor(tt, 16);  tt += __shfl_xor(tt, 32);
            if (lane < 16) {
                atomicAdd(&pos[b * NPTS + row0 + row_l], p);
                atomicAdd(&neg[b * NPTS + row0 + row_l], tt - p);
            }
        }
    }
}

// ---------------------------------------------------------------------------
// Kernel 3: mean of log((p+n)/p) over 32768 rows. Single block, 1024 thr.
// ---------------------------------------------------------------------------
__global__ __launch_bounds__(1024) void finalize_kernel(
    const float* __restrict__ pos, const float* __restrict__ neg,
    float* __restrict__ out)
{
    float acc = 0.0f;
    for (int i = threadIdx.x; i < BATCH * NPTS; i += 1024) {
        float p = pos[i];
        float t = p + neg[i];
        acc += __logf(t / p);   // == -log(p / (p+n))
    }
    #pragma unroll
    for (int off = 32; off; off >>= 1) acc += __shfl_down(acc, off);
    __shared__ float red[16];
    if ((threadIdx.x & 63) == 0) red[threadIdx.x >> 6] = acc;
    __syncthreads();
    if (threadIdx.x < 16) {
        float v = red[threadIdx.x];
        #pragma unroll
        for (int off = 8; off; off >>= 1) v += __shfl_down(v, off);
        if (threadIdx.x == 0) out[0] = v * (1.0f / (BATCH * NPTS));
    }
}

extern "C" void kernel_launch(void* const* d_in, const int* in_sizes, int n_in,
                              void* d_out, int out_size, void* d_ws, size_t ws_size,
                              hipStream_t stream)
{
    const float* features = (const float*)d_in[0];
    const int*   labels   = (const int*)d_in[1];
    float*       out      = (float*)d_out;

    // Workspace: vn bf16 [8][4096][128] = 8 MB, then pos/neg fp32.
    __hip_bfloat16* vn = (__hip_bfloat16*)d_ws;
    float* pos = (float*)((char*)d_ws + (size_t)BATCH * NPTS * CH * sizeof(__hip_bfloat16));
    float* neg = pos + BATCH * NPTS;

    hipLaunchKernelGGL(normalize_kernel, dim3(BATCH * NPTS * 4 / 256), dim3(256), 0, stream,
                       features, vn, pos, neg);
    // 1024 blocks = 32x32 tiles; each block loops over the 8 batches.
    hipLaunchKernelGGL(tile_kernel, dim3(1024), dim3(256), 0, stream,
                       vn, labels, pos, neg);
    hipLaunchKernelGGL(finalize_kernel, dim3(1), dim3(1024), 0, stream, pos, neg, out);
}

// Round 14
// 134.934 us; speedup vs baseline: 1.4822x; 1.2255x over previous
//
#include <hip/hip_runtime.h>
#include <hip/hip_bf16.h>
#include <math.h>

#define BATCH 8
#define NPTS 4096
#define CH 128

// exp(s/TEMP) = 2^(s * 10 * log2(e)). sqrt(10/ln2) is folded into the
// normalize scale so the GEMM accumulator is already the exp2 argument.
#define SQRT_TEMP_LOG2E 3.79828256f   // sqrt(14.4269504089)

typedef __attribute__((ext_vector_type(4))) float f32x4;
typedef __attribute__((ext_vector_type(4))) int   i32x4;
typedef __attribute__((ext_vector_type(8))) short bf16x8;

typedef __attribute__((address_space(3))) unsigned int lds_uint;
typedef __attribute__((address_space(1))) const unsigned int gbl_uint;

__device__ __forceinline__ void load_lds16(const void* g, const void* l) {
    __builtin_amdgcn_global_load_lds((gbl_uint*)g, (lds_uint*)l, 16, 0, 0);
}

// v_exp_f32 is 2^x. (__exp2f collides with a glibc math.h macro.)
__device__ __forceinline__ float fast_exp2(float x) {
    return __builtin_amdgcn_exp2f(x);
}

// ---------------------------------------------------------------------------
// Kernel 1: one-pass L2-normalize (4 threads/point, 32 ch each in registers),
// zero pos/neg.
// ---------------------------------------------------------------------------
__global__ __launch_bounds__(256) void normalize_kernel(
    const float* __restrict__ f, __hip_bfloat16* __restrict__ vn,
    float* __restrict__ pos, float* __restrict__ neg)
{
    int idx = blockIdx.x * 256 + threadIdx.x;   // 0 .. 131071
    int point = idx >> 2, q = idx & 3;
    int b = point >> 12, n = point & (NPTS - 1);
    const float* base = f + (size_t)b * CH * NPTS + (size_t)(q * 32) * NPTS + n;

    float x[32];
    float ss = 0.0f;
    #pragma unroll
    for (int c = 0; c < 32; c++) {
        x[c] = base[(size_t)c * NPTS];
        ss += x[c] * x[c];
    }
    ss += __shfl_xor(ss, 1);
    ss += __shfl_xor(ss, 2);    // 4 lanes of one point share ss
    float scale = SQRT_TEMP_LOG2E / fmaxf(sqrtf(ss), 1e-12f);

    __hip_bfloat16* out = vn + (size_t)point * CH + q * 32;
    #pragma unroll
    for (int c0 = 0; c0 < 32; c0 += 8) {
        union { __hip_bfloat16 h[8]; uint4 u; } pk;
        #pragma unroll
        for (int j = 0; j < 8; j++)
            pk.h[j] = __float2bfloat16(x[c0 + j] * scale);
        *((uint4*)(out + c0)) = pk.u;
    }
    if (q == 0) pos[point] = 0.0f;
    else if (q == 1) neg[point] = 0.0f;
}

// ---------------------------------------------------------------------------
// Kernel 2: R9's exact tile structure, but each block computes TWO row-tiles
// (rt, ct) and (rt+16, ct) against ONE staged B-tile (same ct -> same cols,
// same labC): staging traffic and barrier-drain exposure halve per tile.
//
// Register safety (R11/R12/R13 lessons): acc(64 AGPR, unified file) and a
// fresh afrag(32) must never co-live. afrag2 loads sit behind a
// __syncthreads that the compiler cannot hoist loads across, so the peak
// live set at any instant equals R9's (which compiled to exactly 64+64=128
// at the (256,4) cap with zero spill). WRITE_SIZE ~8 MB is the tripwire.
//
// Intra-block pipelining is dead (R11-R13 all lost to R9): cross-block
// overlap at 4 blocks/CU is this problem's latency-hiding mechanism.
// NO fused finalize (R7/R8: per-block __threadfence serialized the grid).
// ---------------------------------------------------------------------------
__global__ __launch_bounds__(256, 4) void tile_kernel(
    const __hip_bfloat16* __restrict__ vn, const int* __restrict__ labels,
    float* __restrict__ pos, float* __restrict__ neg)
{
    __shared__ short lB[128 * CH];   // 32 KB: the 128 cols of S, row-major
    __shared__ int labC[128];

    const int b   = blockIdx.z;
    const int rtp = blockIdx.y;          // 0..15: row-tile pair
    const int ct  = blockIdx.x;          // 0..31
    const int col0 = ct * 128;
    const __hip_bfloat16* vb = vn + (size_t)b * NPTS * CH;

    const int tid = threadIdx.x;
    const int w = tid >> 6, lane = tid & 63;
    const int lane15 = lane & 15, quad = lane >> 4;

    if (tid < 128) labC[tid] = labels[b * NPTS + col0 + tid];

    // Stage B-tile -> LDS once (both row-tiles share it). XOR chunk swizzle
    // at the global source (LDS dest order is HW-fixed: wave-uniform base +
    // lane*16B). R1..R13: SQ_LDS_BANK_CONFLICT == 0.
    {
        const __hip_bfloat16* Bb = vb + (size_t)col0 * CH;
        #pragma unroll
        for (int i = 0; i < 8; i++) {
            int ldsrow = (w * 8 + i) * 4;           // wave-uniform
            int r = ldsrow + quad;                  // row this lane feeds
            int g = lane15 ^ (r & 15);              // swizzled global chunk
            load_lds16(Bb + (size_t)r * CH + g * 8, &lB[ldsrow * CH]);
        }
    }

    #pragma unroll
    for (int half = 0; half < 2; half++) {
        const int rt = rtp + half * 16;
        const bool diag = (rt == ct);
        const int row0 = rt * 128;

        // A-fragments direct from global for this wave's TWO 16-row blocks.
        // half 0: issued pre-barrier (vmcnt drain covers them, as R9).
        // half 1: issued after the pinning barrier below; lB is already
        // resident so no re-stage, only these register loads are exposed.
        bf16x8 afrag[2][4];
        int lr[2];
        #pragma unroll
        for (int mi = 0; mi < 2; mi++) {
            const int row_l = w * 32 + mi * 16 + lane15;
            const __hip_bfloat16* Arow = vb + (size_t)(row0 + row_l) * CH;
            #pragma unroll
            for (int ks = 0; ks < 4; ks++)
                afrag[mi][ks] = *(const bf16x8*)(Arow + (ks * 4 + quad) * 8);
            lr[mi] = labels[b * NPTS + row0 + row_l];
        }

        if (half == 0) __syncthreads();   // staging + afrag1 vmcnt drain

        // K-loop: each bfrag read feeds both row-blocks. Swapped operands
        // put S-row on lane&15 (in-lane reduction), S-col on quad*4+reg.
        f32x4 acc[2][8] = {};
        #pragma unroll
        for (int ks = 0; ks < 4; ks++) {
            const int koff = ((ks * 4 + quad) ^ lane15) << 3;   // swizzled
            #pragma unroll
            for (int ni = 0; ni < 8; ni++) {
                bf16x8 bf = *(const bf16x8*)&lB[(ni * 16 + lane15) * CH + koff];
                acc[0][ni] = __builtin_amdgcn_mfma_f32_16x16x32_bf16(
                    bf, afrag[0][ks], acc[0][ni], 0, 0, 0);
                acc[1][ni] = __builtin_amdgcn_mfma_f32_16x16x32_bf16(
                    bf, afrag[1][ks], acc[1][ni], 0, 0, 0);
            }
        }

        // Epilogue: in-lane sums, fold quads, 2 atomics per row.
        #pragma unroll
        for (int mi = 0; mi < 2; mi++) {
            const int row_l = w * 32 + mi * 16 + lane15;
            float p = 0.0f, tt = 0.0f;
            if (diag) {
                #pragma unroll
                for (int ni = 0; ni < 8; ni++) {
                    const bool dblk = (ni * 16 == w * 32 + mi * 16);
                    const i32x4 lc = *(const i32x4*)&labC[ni * 16 + quad * 4];
                    #pragma unroll
                    for (int r = 0; r < 4; r++) {
                        float e = fast_exp2(acc[mi][ni][r]);
                        if (dblk && lane15 == quad * 4 + r) e = 0.0f;
                        tt += e;
                        p  += (lc[r] == lr[mi]) ? e : 0.0f;
                    }
                }
            } else {
                #pragma unroll
                for (int ni = 0; ni < 8; ni++) {
                    const i32x4 lc = *(const i32x4*)&labC[ni * 16 + quad * 4];
                    #pragma unroll
                    for (int r = 0; r < 4; r++) {
                        float e = fast_exp2(acc[mi][ni][r]);
                        tt += e;
                        p  += (lc[r] == lr[mi]) ? e : 0.0f;
                    }
                }
            }
            p  += __shfl_xor(p, 16);   p  += __shfl_xor(p, 32);
            tt += __shfl_xor(tt, 16);  tt += __shfl_xor(tt, 32);
            if (lane < 16) {
                atomicAdd(&pos[b * NPTS + row0 + row_l], p);
                atomicAdd(&neg[b * NPTS + row0 + row_l], tt - p);
            }
        }

        // Pin: afrag(half=1) loads must NOT hoist above the epilogue (acc
        // still live there -> R11's spill). Loads cannot cross a barrier.
        if (half == 0) __syncthreads();
    }
}

// ---------------------------------------------------------------------------
// Kernel 3: mean of log((p+n)/p) over 32768 rows. Single block, 1024 thr.
// ---------------------------------------------------------------------------
__global__ __launch_bounds__(1024) void finalize_kernel(
    const float* __restrict__ pos, const float* __restrict__ neg,
    float* __restrict__ out)
{
    float acc = 0.0f;
    for (int i = threadIdx.x; i < BATCH * NPTS; i += 1024) {
        float p = pos[i];
        float t = p + neg[i];
        acc += __logf(t / p);   // == -log(p / (p+n))
    }
    #pragma unroll
    for (int off = 32; off; off >>= 1) acc += __shfl_down(acc, off);
    __shared__ float red[16];
    if ((threadIdx.x & 63) == 0) red[threadIdx.x >> 6] = acc;
    __syncthreads();
    if (threadIdx.x < 16) {
        float v = red[threadIdx.x];
        #pragma unroll
        for (int off = 8; off; off >>= 1) v += __shfl_down(v, off);
        if (threadIdx.x == 0) out[0] = v * (1.0f / (BATCH * NPTS));
    }
}

extern "C" void kernel_launch(void* const* d_in, const int* in_sizes, int n_in,
                              void* d_out, int out_size, void* d_ws, size_t ws_size,
                              hipStream_t stream)
{
    const float* features = (const float*)d_in[0];
    const int*   labels   = (const int*)d_in[1];
    float*       out      = (float*)d_out;

    // Workspace: vn bf16 [8][4096][128] = 8 MB, then pos/neg fp32.
    __hip_bfloat16* vn = (__hip_bfloat16*)d_ws;
    float* pos = (float*)((char*)d_ws + (size_t)BATCH * NPTS * CH * sizeof(__hip_bfloat16));
    float* neg = pos + BATCH * NPTS;

    hipLaunchKernelGGL(normalize_kernel, dim3(BATCH * NPTS * 4 / 256), dim3(256), 0, stream,
                       features, vn, pos, neg);
    // 32 ct x 16 rt-pairs x 8 batches = 4096 blocks, 2 row-tiles each.
    hipLaunchKernelGGL(tile_kernel, dim3(32, 16, BATCH), dim3(256), 0, stream,
                       vn, labels, pos, neg);
    hipLaunchKernelGGL(finalize_kernel, dim3(1), dim3(1024), 0, stream, pos, neg, out);
}